// Round 1
// baseline (1014.384 us; speedup 1.0000x reference)
//
#include <hip/hip_runtime.h>

#define CH 2048
#define HWPIX 196
#define NIMG 256
#define PHID 4096
#define POUT 256

// out layout: q[256*256] | proj_b[256*256] | atten_a[256*196] | atten_b[256*196]
#define Q_OFF 0
#define PB_OFF 65536
#define AA_OFF 131072
#define AB_OFF 181248

typedef __attribute__((ext_vector_type(8))) short short8v;
typedef __attribute__((ext_vector_type(4))) float f32x4;

__device__ __forceinline__ unsigned short f2bf(float x) {
  unsigned int u = __float_as_uint(x);
  u += 0x7fffu + ((u >> 16) & 1u);
  return (unsigned short)(u >> 16);
}
__device__ __forceinline__ float bf2f(unsigned short h) {
  return __uint_as_float(((unsigned int)h) << 16);
}

__device__ __forceinline__ const float* img_ptr(const float* v1, const float* v2, int b) {
  return (b < 128) ? (v1 + (size_t)b * CH * HWPIX) : (v2 + (size_t)(b - 128) * CH * HWPIX);
}

__device__ __forceinline__ float wave_sum(float s) {
#pragma unroll
  for (int off = 32; off; off >>= 1) s += __shfl_xor(s, off);
  return s;
}

// ---- pass 1: pooled[b][c] = mean_hw x ; sumsq[b][hw] += sum_c x^2 (atomic over 8 chunks)
__global__ __launch_bounds__(256) void pool_sumsq(const float* __restrict__ v1,
                                                  const float* __restrict__ v2,
                                                  float* __restrict__ pooled,
                                                  float* __restrict__ sumsq) {
  int b = blockIdx.x >> 3, chunk = blockIdx.x & 7;
  const float* img = img_ptr(v1, v2, b);
  int lane = threadIdx.x & 63, w = threadIdx.x >> 6;
  float sq0 = 0.f, sq1 = 0.f, sq2 = 0.f, sq3 = 0.f;
  int c0 = chunk * 256;
#pragma unroll 4
  for (int cc = w; cc < 256; cc += 4) {
    int c = c0 + cc;
    const float* row = img + (size_t)c * HWPIX;
    float a0 = row[lane];
    float a1 = row[64 + lane];
    float a2 = row[128 + lane];
    float a3 = (lane < 4) ? row[192 + lane] : 0.f;
    sq0 += a0 * a0; sq1 += a1 * a1; sq2 += a2 * a2; sq3 += a3 * a3;
    float s = wave_sum(a0 + a1 + a2 + a3);
    if (lane == 0) pooled[(size_t)b * CH + c] = s * (1.f / 196.f);
  }
  __shared__ float lds[4][4][64];
  lds[w][0][lane] = sq0; lds[w][1][lane] = sq1; lds[w][2][lane] = sq2; lds[w][3][lane] = sq3;
  __syncthreads();
  int p = threadIdx.x;
  if (p < HWPIX) {
    int sl = p >> 6, ln = p & 63;
    float t = lds[0][sl][ln] + lds[1][sl][ln] + lds[2][sl][ln] + lds[3][sl][ln];
    atomicAdd(&sumsq[(size_t)b * HWPIX + p], t);
  }
}

// ---- normalize pooled rows in place -> p_hat
__global__ __launch_bounds__(256) void normalize_rows(float* __restrict__ pooled) {
  int b = blockIdx.x, tid = threadIdx.x;
  float* row = pooled + (size_t)b * CH;
  float v[8];
  float s = 0.f;
#pragma unroll
  for (int i = 0; i < 8; ++i) { v[i] = row[tid + i * 256]; s += v[i] * v[i]; }
  s = wave_sum(s);
  __shared__ float red[4];
  if ((tid & 63) == 0) red[tid >> 6] = s;
  __syncthreads();
  float tot = red[0] + red[1] + red[2] + red[3];
  float scale = 1.f / fmaxf(sqrtf(tot), 1e-12f);
#pragma unroll
  for (int i = 0; i < 8; ++i) row[tid + i * 256] = v[i] * scale;
}

// ---- pass 2: dot[b][hw] += sum_c x[b,c,hw] * p_hat[b^128][c]  (atomic over 8 chunks)
__global__ __launch_bounds__(256) void dot_partial(const float* __restrict__ v1,
                                                   const float* __restrict__ v2,
                                                   const float* __restrict__ phat,
                                                   float* __restrict__ dotb) {
  int b = blockIdx.x >> 3, chunk = blockIdx.x & 7;
  const float* img = img_ptr(v1, v2, b);
  const float* p = phat + (size_t)(b ^ 128) * CH;
  int lane = threadIdx.x & 63, w = threadIdx.x >> 6;
  float d0 = 0.f, d1 = 0.f, d2 = 0.f, d3 = 0.f;
  int c0 = chunk * 256;
#pragma unroll 4
  for (int cc = w; cc < 256; cc += 4) {
    int c = c0 + cc;
    const float* row = img + (size_t)c * HWPIX;
    float pc = p[c];
    d0 += row[lane] * pc;
    d1 += row[64 + lane] * pc;
    d2 += row[128 + lane] * pc;
    if (lane < 4) d3 += row[192 + lane] * pc;
  }
  __shared__ float lds[4][4][64];
  lds[w][0][lane] = d0; lds[w][1][lane] = d1; lds[w][2][lane] = d2; lds[w][3][lane] = d3;
  __syncthreads();
  int p2 = threadIdx.x;
  if (p2 < HWPIX) {
    int sl = p2 >> 6, ln = p2 & 63;
    float t = lds[0][sl][ln] + lds[1][sl][ln] + lds[2][sl][ln] + lds[3][sl][ln];
    atomicAdd(&dotb[(size_t)b * HWPIX + p2], t);
  }
}

// ---- attention finalize: cos -> (cos+1)/2 -> /denom ; write atten_a and swapped atten_b
__global__ __launch_bounds__(256) void atten_final(const float* __restrict__ dotb,
                                                   const float* __restrict__ sumsq,
                                                   float* __restrict__ out) {
  int b = blockIdx.x, tid = threadIdx.x;
  float a = 0.f;
  if (tid < HWPIX) {
    float d = dotb[(size_t)b * HWPIX + tid];
    float npx = sqrtf(sumsq[(size_t)b * HWPIX + tid]);
    float cosv = d / fmaxf(npx, 1e-12f);
    a = (cosv + 1.f) * 0.5f;
  }
  float s = wave_sum(fabsf(a));
  __shared__ float red[4];
  if ((tid & 63) == 0) red[tid >> 6] = s;
  __syncthreads();
  float denom = fmaxf(red[0] + red[1] + red[2] + red[3], 1e-12f);
  if (tid < HWPIX) {
    float att = a / denom;
    out[AA_OFF + (size_t)b * HWPIX + tid] = att;
    out[AB_OFF + (size_t)(b ^ 128) * HWPIX + tid] = att;
  }
}

// ---- pass 3: ea[b][c] = sum_hw x[b,c,hw] * atten_a[b,hw]
__global__ __launch_bounds__(256) void ea_kernel(const float* __restrict__ v1,
                                                 const float* __restrict__ v2,
                                                 const float* __restrict__ out,
                                                 float* __restrict__ ea) {
  int b = blockIdx.x >> 3, chunk = blockIdx.x & 7;
  const float* img = img_ptr(v1, v2, b);
  const float* att = out + AA_OFF + (size_t)b * HWPIX;
  int lane = threadIdx.x & 63, w = threadIdx.x >> 6;
  float a0 = att[lane];
  float a1 = att[64 + lane];
  float a2 = att[128 + lane];
  float a3 = (lane < 4) ? att[192 + lane] : 0.f;
  int c0 = chunk * 256;
#pragma unroll 4
  for (int cc = w; cc < 256; cc += 4) {
    int c = c0 + cc;
    const float* row = img + (size_t)c * HWPIX;
    float s = row[lane] * a0 + row[64 + lane] * a1 + row[128 + lane] * a2;
    if (lane < 4) s += row[192 + lane] * a3;
    s = wave_sum(s);
    if (lane == 0) ea[(size_t)b * CH + c] = s;
  }
}

// ---- GEMM: C[M][N] = A[M][K] @ B[K][N] + bias, fp32 in/out, bf16 hi/lo MFMA (3 products)
__global__ __launch_bounds__(256) void gemm_hilo(const float* __restrict__ A,
                                                 const float* __restrict__ B,
                                                 const float* __restrict__ bias,
                                                 float* __restrict__ C,
                                                 int M, int N, int K) {
  const int LDT = 40;  // padded LDS row stride (elements)
  __shared__ short Ah[64 * 40], Al[64 * 40], Bh[64 * 40], Bl[64 * 40];
  int tid = threadIdx.x;
  int lane = tid & 63, wid = tid >> 6;
  int wm = wid & 1, wn = wid >> 1;
  int m0 = blockIdx.x * 64, n0 = blockIdx.y * 64;

  f32x4 acc[2][2] = {};
  int ar = tid >> 2, akg = tid & 3;
  int bn_ = tid & 63, bkg = tid >> 6;

  for (int k0 = 0; k0 < K; k0 += 32) {
    __syncthreads();
    {  // stage A 64x32
      const float* src = A + (size_t)(m0 + ar) * K + k0 + akg * 8;
      float f[8];
      *(float4*)(f) = *(const float4*)(src);
      *(float4*)(f + 4) = *(const float4*)(src + 4);
      short8v hi, lo;
#pragma unroll
      for (int i = 0; i < 8; ++i) {
        unsigned short h_ = f2bf(f[i]);
        hi[i] = (short)h_;
        lo[i] = (short)f2bf(f[i] - bf2f(h_));
      }
      *(short8v*)&Ah[ar * LDT + akg * 8] = hi;
      *(short8v*)&Al[ar * LDT + akg * 8] = lo;
    }
    {  // stage B 32x64 transposed -> [n][k]
      const float* src = B + (size_t)(k0 + bkg * 8) * N + n0 + bn_;
      float f[8];
#pragma unroll
      for (int i = 0; i < 8; ++i) f[i] = src[(size_t)i * N];
      short8v hi, lo;
#pragma unroll
      for (int i = 0; i < 8; ++i) {
        unsigned short h_ = f2bf(f[i]);
        hi[i] = (short)h_;
        lo[i] = (short)f2bf(f[i] - bf2f(h_));
      }
      *(short8v*)&Bh[bn_ * LDT + bkg * 8] = hi;
      *(short8v*)&Bl[bn_ * LDT + bkg * 8] = lo;
    }
    __syncthreads();
    int kr = lane >> 4, fr = lane & 15;
    short8v ah[2], al2[2], bh[2], bl2[2];
#pragma unroll
    for (int mi = 0; mi < 2; ++mi) {
      int row = wm * 32 + mi * 16 + fr;
      ah[mi] = *(short8v*)&Ah[row * LDT + kr * 8];
      al2[mi] = *(short8v*)&Al[row * LDT + kr * 8];
    }
#pragma unroll
    for (int ni = 0; ni < 2; ++ni) {
      int col = wn * 32 + ni * 16 + fr;
      bh[ni] = *(short8v*)&Bh[col * LDT + kr * 8];
      bl2[ni] = *(short8v*)&Bl[col * LDT + kr * 8];
    }
#pragma unroll
    for (int mi = 0; mi < 2; ++mi)
#pragma unroll
      for (int ni = 0; ni < 2; ++ni) {
        acc[mi][ni] = __builtin_amdgcn_mfma_f32_16x16x32_bf16(al2[mi], bh[ni], acc[mi][ni], 0, 0, 0);
        acc[mi][ni] = __builtin_amdgcn_mfma_f32_16x16x32_bf16(ah[mi], bl2[ni], acc[mi][ni], 0, 0, 0);
        acc[mi][ni] = __builtin_amdgcn_mfma_f32_16x16x32_bf16(ah[mi], bh[ni], acc[mi][ni], 0, 0, 0);
      }
  }
  int kr = lane >> 4, fr = lane & 15;
#pragma unroll
  for (int mi = 0; mi < 2; ++mi)
#pragma unroll
    for (int ni = 0; ni < 2; ++ni) {
      int col = n0 + wn * 32 + ni * 16 + fr;
      float bv = bias[col];
#pragma unroll
      for (int r = 0; r < 4; ++r) {
        int row = m0 + wm * 32 + mi * 16 + kr * 4 + r;
        C[(size_t)row * N + col] = acc[mi][ni][r] + bv;
      }
    }
}

// ---- batchnorm (over 256 rows) + relu, one thread per column
__global__ __launch_bounds__(256) void bn_relu(const float* __restrict__ h,
                                               const float* __restrict__ g,
                                               const float* __restrict__ be,
                                               float* __restrict__ outp, int N) {
  int col = blockIdx.x * 256 + threadIdx.x;
  float s = 0.f, s2 = 0.f;
  for (int r = 0; r < 256; ++r) {
    float v = h[(size_t)r * N + col];
    s += v; s2 += v * v;
  }
  float m = s * (1.f / 256.f);
  float var = s2 * (1.f / 256.f) - m * m;
  float sc = rsqrtf(var + 1e-5f) * g[col];
  float sh = be[col] - m * sc;
  for (int r = 0; r < 256; ++r) {
    float v = h[(size_t)r * N + col] * sc + sh;
    outp[(size_t)r * N + col] = v > 0.f ? v : 0.f;
  }
}

// ---- proj_b = proj_a with halves swapped
__global__ __launch_bounds__(256) void swap_rows(const float* __restrict__ proj,
                                                 float* __restrict__ outp) {
  int i = blockIdx.x * 256 + threadIdx.x;  // 65536
  int r = i >> 8, c = i & 255;
  outp[i] = proj[(size_t)((r ^ 128) << 8) + c];
}

extern "C" void kernel_launch(void* const* d_in, const int* in_sizes, int n_in,
                              void* d_out, int out_size, void* d_ws, size_t ws_size,
                              hipStream_t stream) {
  const float* v1 = (const float*)d_in[0];
  const float* v2 = (const float*)d_in[1];
  const float* W1 = (const float*)d_in[3];
  const float* b1 = (const float*)d_in[4];
  const float* g1 = (const float*)d_in[5];
  const float* be1 = (const float*)d_in[6];
  const float* W2 = (const float*)d_in[7];
  const float* b2 = (const float*)d_in[8];
  const float* P1 = (const float*)d_in[9];
  const float* pb1 = (const float*)d_in[10];
  const float* pg1 = (const float*)d_in[11];
  const float* pbe1 = (const float*)d_in[12];
  const float* P2 = (const float*)d_in[13];
  const float* pb2 = (const float*)d_in[14];
  float* out = (float*)d_out;
  float* ws = (float*)d_ws;

  float* pooled = ws;                // 256*2048 = 524288
  float* sumsq = ws + 524288;        // 50176
  float* dotb = ws + 574464;         // 50176
  float* ea = ws + 624640;           // 524288
  float* h = ws + 1148928;           // 1048576
  float* act = ws + 2197504;         // 1048576
  float* proj = ws + 3246080;        // 65536

  hipMemsetAsync(sumsq, 0, (size_t)(50176 * 2) * sizeof(float), stream);
  hipLaunchKernelGGL(pool_sumsq, dim3(2048), dim3(256), 0, stream, v1, v2, pooled, sumsq);
  hipLaunchKernelGGL(normalize_rows, dim3(256), dim3(256), 0, stream, pooled);
  hipLaunchKernelGGL(dot_partial, dim3(2048), dim3(256), 0, stream, v1, v2, pooled, dotb);
  hipLaunchKernelGGL(atten_final, dim3(256), dim3(256), 0, stream, dotb, sumsq, out);
  hipLaunchKernelGGL(ea_kernel, dim3(2048), dim3(256), 0, stream, v1, v2, out, ea);

  hipLaunchKernelGGL(gemm_hilo, dim3(4, PHID / 64), dim3(256), 0, stream, ea, W1, b1, h, 256, PHID, CH);
  hipLaunchKernelGGL(bn_relu, dim3(PHID / 256), dim3(256), 0, stream, h, g1, be1, act, PHID);
  hipLaunchKernelGGL(gemm_hilo, dim3(4, POUT / 64), dim3(256), 0, stream, act, W2, b2, proj, 256, POUT, PHID);
  hipLaunchKernelGGL(swap_rows, dim3(256), dim3(256), 0, stream, proj, out + PB_OFF);
  hipLaunchKernelGGL(gemm_hilo, dim3(4, PHID / 64), dim3(256), 0, stream, proj, P1, pb1, h, 256, PHID, POUT);
  hipLaunchKernelGGL(bn_relu, dim3(PHID / 256), dim3(256), 0, stream, h, pg1, pbe1, act, PHID);
  hipLaunchKernelGGL(gemm_hilo, dim3(4, POUT / 64), dim3(256), 0, stream, act, P2, pb2, out, 256, POUT, PHID);
}

// Round 7
// 740.113 us; speedup vs baseline: 1.3706x; 1.3706x over previous
//
#include <hip/hip_runtime.h>
#include <stdint.h>

#define CH 2048
#define HWPIX 196
#define HW4 49
#define NIMG 256
#define PH 4096
#define PO 256

// out layout: q[256*256] | proj_b[256*256] | atten_a[256*196] | atten_b[256*196]
#define Q_OFF 0
#define PB_OFF 65536
#define AA_OFF 131072
#define AB_OFF 181248

typedef __attribute__((ext_vector_type(8))) short short8v;
typedef __attribute__((ext_vector_type(4))) float f32x4;
typedef unsigned short u16;
typedef unsigned int u32;

__device__ __forceinline__ u16 f2bf(float x) {
  u32 u = __float_as_uint(x);
  u += 0x7fffu + ((u >> 16) & 1u);
  return (u16)(u >> 16);
}
__device__ __forceinline__ float bf2f(u16 h) { return __uint_as_float(((u32)h) << 16); }

__device__ __forceinline__ const float* img_ptr(const float* v1, const float* v2, int b) {
  return (b < 128) ? (v1 + (size_t)b * CH * HWPIX) : (v2 + (size_t)(b - 128) * CH * HWPIX);
}

__device__ __forceinline__ float wave_sum(float s) {
#pragma unroll
  for (int off = 32; off; off >>= 1) s += __shfl_xor(s, off);
  return s;
}

// ================= pass 1: pooled[b][c], sumsq partials per chunk ==============
// grid 2048 (256 images x 8 chunks), block 256. No shfl in hot loop.
__global__ __launch_bounds__(256) void pool_sumsq(const float* __restrict__ v1,
                                                  const float* __restrict__ v2,
                                                  float* __restrict__ pooled,
                                                  float* __restrict__ sums_part) {
  int b = blockIdx.x >> 3, chunk = blockIdx.x & 7;
  const float* img = img_ptr(v1, v2, b) + (size_t)chunk * 256 * HWPIX;
  int tid = threadIdx.x, lane = tid & 63, w = tid >> 6;
  __shared__ float stage[4][32][53];
  __shared__ float sqs[4][HWPIX];
  f32x4 sq = {0.f, 0.f, 0.f, 0.f};
#pragma unroll
  for (int batch = 0; batch < 2; ++batch) {
#pragma unroll 8
    for (int i = 0; i < 32; ++i) {
      int c = w * 64 + batch * 32 + i;
      f32x4 v = {0.f, 0.f, 0.f, 0.f};
      if (lane < HW4) v = *(const f32x4*)(img + (size_t)c * HWPIX + lane * 4);
      sq += v * v;
      if (lane < HW4) stage[w][i][lane] = v.x + v.y + v.z + v.w;
    }
    __syncthreads();
    if (tid < 128) {
      int wr = tid >> 5, ir = tid & 31;
      float s = 0.f;
      for (int l = 0; l < HW4; ++l) s += stage[wr][ir][l];
      int c = wr * 64 + batch * 32 + ir;
      pooled[(size_t)b * CH + chunk * 256 + c] = s * (1.f / 196.f);
    }
    __syncthreads();
  }
  if (lane < HW4) *(f32x4*)&sqs[w][lane * 4] = sq;
  __syncthreads();
  if (tid < HWPIX) {
    float s = sqs[0][tid] + sqs[1][tid] + sqs[2][tid] + sqs[3][tid];
    sums_part[((size_t)b * 8 + chunk) * HWPIX + tid] = s;
  }
}

// ===== fused: normalize pooled(partner) -> dot -> attention -> ea (hi/lo bf16) =====
// grid 256 (one block per image), block 1024 (16 waves).
__global__ __launch_bounds__(1024) void fused_atten(const float* __restrict__ v1,
                                                    const float* __restrict__ v2,
                                                    const float* __restrict__ pooled,
                                                    const float* __restrict__ sums_part,
                                                    float* __restrict__ out,
                                                    u16* __restrict__ ea_hi,
                                                    u16* __restrict__ ea_lo) {
  int b = blockIdx.x;
  const float* img = img_ptr(v1, v2, b);
  int tid = threadIdx.x, lane = tid & 63, w = tid >> 6;
  __shared__ float phat[CH];
  __shared__ float dots[16][HWPIX];
  __shared__ float att[HWPIX];
  __shared__ float red[16];

  // P0: normalize pooled[b^128] into phat
  const float* pr = pooled + (size_t)(b ^ 128) * CH;
  float x0 = pr[tid], x1 = pr[tid + 1024];
  float s = wave_sum(x0 * x0 + x1 * x1);
  if (lane == 0) red[w] = s;
  __syncthreads();
  float tot = 0.f;
#pragma unroll
  for (int i = 0; i < 16; ++i) tot += red[i];
  float scale = 1.f / fmaxf(sqrtf(tot), 1e-12f);
  phat[tid] = x0 * scale;
  phat[tid + 1024] = x1 * scale;
  __syncthreads();

  // P1: dot partials; wave w owns channels [128w, 128w+128)
  f32x4 dacc = {0.f, 0.f, 0.f, 0.f};
  const float* base = img + (size_t)w * 128 * HWPIX;
#pragma unroll 8
  for (int i = 0; i < 128; ++i) {
    f32x4 v = {0.f, 0.f, 0.f, 0.f};
    if (lane < HW4) v = *(const f32x4*)(base + (size_t)i * HWPIX + lane * 4);
    float pc = phat[w * 128 + i];
    dacc += v * pc;
  }
  if (lane < HW4) *(f32x4*)&dots[w][lane * 4] = dacc;
  __syncthreads();

  // P2: attention
  float a = 0.f;
  if (tid < HWPIX) {
    float d = 0.f, ss = 0.f;
#pragma unroll
    for (int wv = 0; wv < 16; ++wv) d += dots[wv][tid];
#pragma unroll
    for (int k = 0; k < 8; ++k) ss += sums_part[((size_t)b * 8 + k) * HWPIX + tid];
    float cosv = d / fmaxf(sqrtf(ss), 1e-12f);
    a = (cosv + 1.f) * 0.5f;
  }
  float sa = wave_sum(fabsf(a));
  if (lane == 0) red[w] = sa;
  __syncthreads();
  float denom = fmaxf(red[0] + red[1] + red[2] + red[3], 1e-12f);
  if (tid < HWPIX) {
    float atv = a / denom;
    out[AA_OFF + (size_t)b * HWPIX + tid] = atv;
    out[AB_OFF + (size_t)(b ^ 128) * HWPIX + tid] = atv;
    att[tid] = atv;
  }
  __syncthreads();

  // P3: ea[c] = sum_p x[c][p]*att[p]; thread-per-channel, no cross-lane
#pragma unroll
  for (int cc = 0; cc < 2; ++cc) {
    int c = tid + cc * 1024;
    const float* row = img + (size_t)c * HWPIX;
    float acc = 0.f;
#pragma unroll 8
    for (int j = 0; j < HW4; ++j) {
      f32x4 v = *(const f32x4*)(row + j * 4);
      acc += v.x * att[j * 4 + 0] + v.y * att[j * 4 + 1] + v.z * att[j * 4 + 2] + v.w * att[j * 4 + 3];
    }
    u16 hh = f2bf(acc);
    ea_hi[(size_t)b * CH + c] = hh;
    ea_lo[(size_t)b * CH + c] = f2bf(acc - bf2f(hh));
  }
}

// ===== weight convert + transpose: W[K][N] f32 -> Wt_hi/Wt_lo [N][K] bf16 =====
__global__ __launch_bounds__(256) void wconv(const float* __restrict__ W,
                                             u16* __restrict__ hi, u16* __restrict__ lo,
                                             int K, int N) {
  __shared__ u16 th[64][72], tl[64][72];
  int k0 = blockIdx.x * 64, n0 = blockIdx.y * 64;
  int tid = threadIdx.x;
  int r = tid >> 4, c4 = (tid & 15) * 4;
#pragma unroll
  for (int p = 0; p < 4; ++p) {
    int k = r + p * 16;
    f32x4 v = *(const f32x4*)(W + (size_t)(k0 + k) * N + n0 + c4);
#pragma unroll
    for (int i = 0; i < 4; ++i) {
      u16 h = f2bf(v[i]);
      th[c4 + i][k] = h;
      tl[c4 + i][k] = f2bf(v[i] - bf2f(h));
    }
  }
  __syncthreads();
  int n = tid >> 2, kq = (tid & 3) * 16;
  u16* dh = hi + (size_t)(n0 + n) * K + k0 + kq;
  u16* dl = lo + (size_t)(n0 + n) * K + k0 + kq;
  *(short8v*)dh = *(const short8v*)&th[n][kq];
  *(short8v*)(dh + 8) = *(const short8v*)&th[n][kq + 8];
  *(short8v*)dl = *(const short8v*)&tl[n][kq];
  *(short8v*)(dl + 8) = *(const short8v*)&tl[n][kq + 8];
}

// ===== GEMM: C = A @ B^T(+bias), A=[M][K] hi/lo bf16, Bt=[N][K] hi/lo bf16 =====
// 64x64 tile, BK=64, double-buffered global_load_lds with XOR-swizzled source.
#define GLOAD16(g, l)                                                                  \
  __builtin_amdgcn_global_load_lds((const __attribute__((address_space(1))) u32*)(g),  \
                                   (__attribute__((address_space(3))) u32*)(l), 16, 0, 0)

__global__ __launch_bounds__(256) void gemm_hilo(const u16* __restrict__ Ahi, const u16* __restrict__ Alo,
                                                 const u16* __restrict__ Bhi, const u16* __restrict__ Blo,
                                                 const float* __restrict__ bias, float* __restrict__ C,
                                                 float* __restrict__ Cpart, int M, int N, int K) {
  __shared__ __align__(16) u16 lds[2][4][4096];
  int tid = threadIdx.x, lane = tid & 63;
  int wid = tid >> 6, wm = wid & 1, wn = wid >> 1;
  int m0 = blockIdx.x * 64, n0 = blockIdx.y * 64;
  int z = blockIdx.z, nz = gridDim.z;
  int kLen = K / nz, k00 = z * kLen, nt = kLen / 64;
  int r0 = tid >> 3, kc_lin = (tid & 7) * 8;
  int ldsoff = (tid & 192) * 8;  // w*512 shorts
  f32x4 acc[2][2] = {};

  auto stage = [&](int buf, int t) {
    int kk0 = k00 + t * 64;
#pragma unroll
    for (int sdx = 0; sdx < 2; ++sdx) {
      int r = sdx * 32 + r0;
      int kc = kc_lin ^ ((r & 7) << 3);
      GLOAD16(Ahi + (size_t)(m0 + r) * K + kk0 + kc, &lds[buf][0][sdx * 2048 + ldsoff]);
      GLOAD16(Alo + (size_t)(m0 + r) * K + kk0 + kc, &lds[buf][1][sdx * 2048 + ldsoff]);
      GLOAD16(Bhi + (size_t)(n0 + r) * K + kk0 + kc, &lds[buf][2][sdx * 2048 + ldsoff]);
      GLOAD16(Blo + (size_t)(n0 + r) * K + kk0 + kc, &lds[buf][3][sdx * 2048 + ldsoff]);
    }
  };

  stage(0, 0);
  __syncthreads();
  int kr = lane >> 4, fr = lane & 15;
  for (int t = 0; t < nt; ++t) {
    int cur = t & 1;
    if (t + 1 < nt) stage(cur ^ 1, t + 1);
#pragma unroll
    for (int kk = 0; kk < 2; ++kk) {
      short8v ah[2], al[2], bh[2], bl[2];
#pragma unroll
      for (int mi = 0; mi < 2; ++mi) {
        int row = wm * 32 + mi * 16 + fr;
        int ks = (kk * 32 + kr * 8) ^ ((row & 7) << 3);
        ah[mi] = *(const short8v*)(&lds[cur][0][row * 64 + ks]);
        al[mi] = *(const short8v*)(&lds[cur][1][row * 64 + ks]);
      }
#pragma unroll
      for (int ni = 0; ni < 2; ++ni) {
        int row = wn * 32 + ni * 16 + fr;
        int ks = (kk * 32 + kr * 8) ^ ((row & 7) << 3);
        bh[ni] = *(const short8v*)(&lds[cur][2][row * 64 + ks]);
        bl[ni] = *(const short8v*)(&lds[cur][3][row * 64 + ks]);
      }
#pragma unroll
      for (int mi = 0; mi < 2; ++mi)
#pragma unroll
        for (int ni = 0; ni < 2; ++ni) {
          acc[mi][ni] = __builtin_amdgcn_mfma_f32_16x16x32_bf16(al[mi], bh[ni], acc[mi][ni], 0, 0, 0);
          acc[mi][ni] = __builtin_amdgcn_mfma_f32_16x16x32_bf16(ah[mi], bl[ni], acc[mi][ni], 0, 0, 0);
          acc[mi][ni] = __builtin_amdgcn_mfma_f32_16x16x32_bf16(ah[mi], bh[ni], acc[mi][ni], 0, 0, 0);
        }
    }
    __syncthreads();
  }

  if (nz > 1) {
#pragma unroll
    for (int mi = 0; mi < 2; ++mi)
#pragma unroll
      for (int ni = 0; ni < 2; ++ni) {
        int col = n0 + wn * 32 + ni * 16 + fr;
#pragma unroll
        for (int rr = 0; rr < 4; ++rr) {
          int row = m0 + wm * 32 + mi * 16 + kr * 4 + rr;
          Cpart[((size_t)z * M + row) * N + col] = acc[mi][ni][rr];
        }
      }
  } else {
#pragma unroll
    for (int mi = 0; mi < 2; ++mi)
#pragma unroll
      for (int ni = 0; ni < 2; ++ni) {
        int col = n0 + wn * 32 + ni * 16 + fr;
        float bv = bias[col];
#pragma unroll
        for (int rr = 0; rr < 4; ++rr) {
          int row = m0 + wm * 32 + mi * 16 + kr * 4 + rr;
          C[(size_t)row * N + col] = acc[mi][ni][rr] + bv;
        }
      }
  }
}

// ===== batchnorm(256 rows)+relu -> bf16 hi/lo.  grid N/64, block 256 =====
__global__ __launch_bounds__(256) void bn_relu_conv(const float* __restrict__ h,
                                                    const float* __restrict__ g,
                                                    const float* __restrict__ be,
                                                    u16* __restrict__ ahi, u16* __restrict__ alo,
                                                    int N) {
  int tid = threadIdx.x, cl = tid & 63, q = tid >> 6;
  int c = blockIdx.x * 64 + cl;
  __shared__ float s1[4][64], s2[4][64], scv[64], shv[64];
  float s = 0.f, ss = 0.f;
#pragma unroll 4
  for (int r = q * 64; r < q * 64 + 64; ++r) {
    float v = h[(size_t)r * N + c];
    s += v; ss += v * v;
  }
  s1[q][cl] = s; s2[q][cl] = ss;
  __syncthreads();
  if (tid < 64) {
    float S = s1[0][tid] + s1[1][tid] + s1[2][tid] + s1[3][tid];
    float S2 = s2[0][tid] + s2[1][tid] + s2[2][tid] + s2[3][tid];
    float m = S * (1.f / 256.f);
    float var = S2 * (1.f / 256.f) - m * m;
    float sc = rsqrtf(var + 1e-5f) * g[blockIdx.x * 64 + tid];
    scv[tid] = sc;
    shv[tid] = be[blockIdx.x * 64 + tid] - m * sc;
  }
  __syncthreads();
  float sc = scv[cl], sh = shv[cl];
#pragma unroll 4
  for (int r = q * 64; r < q * 64 + 64; ++r) {
    float v = h[(size_t)r * N + c] * sc + sh;
    v = v > 0.f ? v : 0.f;
    u16 hh = f2bf(v);
    ahi[(size_t)r * N + c] = hh;
    alo[(size_t)r * N + c] = f2bf(v - bf2f(hh));
  }
}

// ===== split-K reduce (+bias), optional hi/lo output.  65536 elems =====
__global__ __launch_bounds__(256) void red8(const float* __restrict__ parts,
                                            const float* __restrict__ bias,
                                            float* __restrict__ C,
                                            u16* __restrict__ Chi, u16* __restrict__ Clo) {
  int i = blockIdx.x * 256 + threadIdx.x;
  float s = 0.f;
#pragma unroll
  for (int zz = 0; zz < 8; ++zz) s += parts[zz * 65536 + i];
  s += bias[i & 255];
  C[i] = s;
  if (Chi) {
    u16 hh = f2bf(s);
    Chi[i] = hh;
    Clo[i] = f2bf(s - bf2f(hh));
  }
}

__global__ __launch_bounds__(256) void swap_rows(const float* __restrict__ proj,
                                                 float* __restrict__ outp) {
  int i = blockIdx.x * 256 + threadIdx.x;
  int r = i >> 8, c = i & 255;
  outp[i] = proj[(size_t)((r ^ 128) << 8) + c];
}

extern "C" void kernel_launch(void* const* d_in, const int* in_sizes, int n_in,
                              void* d_out, int out_size, void* d_ws, size_t ws_size,
                              hipStream_t stream) {
  const float* v1 = (const float*)d_in[0];
  const float* v2 = (const float*)d_in[1];
  const float* W1 = (const float*)d_in[3];
  const float* b1 = (const float*)d_in[4];
  const float* g1 = (const float*)d_in[5];
  const float* be1 = (const float*)d_in[6];
  const float* W2 = (const float*)d_in[7];
  const float* b2 = (const float*)d_in[8];
  const float* P1 = (const float*)d_in[9];
  const float* pb1 = (const float*)d_in[10];
  const float* pg1 = (const float*)d_in[11];
  const float* pbe1 = (const float*)d_in[12];
  const float* P2 = (const float*)d_in[13];
  const float* pb2 = (const float*)d_in[14];
  float* out = (float*)d_out;
  float* ws = (float*)d_ws;

  float* pooled = ws;                          // 524288 f
  float* sums_part = pooled + 524288;          // 401408 f
  float* h = sums_part + 401408;               // 1048576 f
  float* proj = h + 1048576;                   // 65536 f
  float* parts = proj + 65536;                 // 524288 f
  u16* ea_hi = (u16*)(parts + 524288);         // 524288 u16
  u16* ea_lo = ea_hi + 524288;
  u16* act_hi = ea_lo + 524288;                // 1048576 u16
  u16* act_lo = act_hi + 1048576;
  u16* proj_hi = act_lo + 1048576;             // 65536 u16
  u16* proj_lo = proj_hi + 65536;
  u16* W1t_hi = proj_lo + 65536;               // 8388608 u16
  u16* W1t_lo = W1t_hi + 8388608;
  u16* W2t_hi = W1t_lo + 8388608;              // 1048576 u16
  u16* W2t_lo = W2t_hi + 1048576;
  u16* P1t_hi = W2t_lo + 1048576;              // 1048576 u16
  u16* P1t_lo = P1t_hi + 1048576;
  u16* P2t_hi = P1t_lo + 1048576;              // 1048576 u16
  u16* P2t_lo = P2t_hi + 1048576;

  // streaming pipeline
  hipLaunchKernelGGL(pool_sumsq, dim3(2048), dim3(256), 0, stream, v1, v2, pooled, sums_part);
  hipLaunchKernelGGL(fused_atten, dim3(256), dim3(1024), 0, stream, v1, v2, pooled, sums_part,
                     out, ea_hi, ea_lo);

  // weight conversions (independent of streaming results)
  hipLaunchKernelGGL(wconv, dim3(CH / 64, PH / 64), dim3(256), 0, stream, W1, W1t_hi, W1t_lo, CH, PH);
  hipLaunchKernelGGL(wconv, dim3(PH / 64, PO / 64), dim3(256), 0, stream, W2, W2t_hi, W2t_lo, PH, PO);
  hipLaunchKernelGGL(wconv, dim3(PO / 64, PH / 64), dim3(256), 0, stream, P1, P1t_hi, P1t_lo, PO, PH);
  hipLaunchKernelGGL(wconv, dim3(PH / 64, PO / 64), dim3(256), 0, stream, P2, P2t_hi, P2t_lo, PH, PO);

  // MLP 1: h = ea@W1+b1 ; act = relu(bn(h)) ; proj = act@W2+b2
  hipLaunchKernelGGL(gemm_hilo, dim3(4, PH / 64, 1), dim3(256), 0, stream,
                     ea_hi, ea_lo, W1t_hi, W1t_lo, b1, h, (float*)nullptr, 256, PH, CH);
  hipLaunchKernelGGL(bn_relu_conv, dim3(PH / 64), dim3(256), 0, stream, h, g1, be1, act_hi, act_lo, PH);
  hipLaunchKernelGGL(gemm_hilo, dim3(4, PO / 64, 8), dim3(256), 0, stream,
                     act_hi, act_lo, W2t_hi, W2t_lo, (const float*)nullptr, (float*)nullptr, parts,
                     256, PO, PH);
  hipLaunchKernelGGL(red8, dim3(256), dim3(256), 0, stream, parts, b2, proj, proj_hi, proj_lo);
  hipLaunchKernelGGL(swap_rows, dim3(256), dim3(256), 0, stream, proj, out + PB_OFF);

  // MLP 2 (predictor): q = mlp(proj)
  hipLaunchKernelGGL(gemm_hilo, dim3(4, PH / 64, 1), dim3(256), 0, stream,
                     proj_hi, proj_lo, P1t_hi, P1t_lo, pb1, h, (float*)nullptr, 256, PH, PO);
  hipLaunchKernelGGL(bn_relu_conv, dim3(PH / 64), dim3(256), 0, stream, h, pg1, pbe1, act_hi, act_lo, PH);
  hipLaunchKernelGGL(gemm_hilo, dim3(4, PO / 64, 8), dim3(256), 0, stream,
                     act_hi, act_lo, P2t_hi, P2t_lo, (const float*)nullptr, (float*)nullptr, parts,
                     256, PO, PH);
  hipLaunchKernelGGL(red8, dim3(256), dim3(256), 0, stream, parts, pb2, out + Q_OFF,
                     (u16*)nullptr, (u16*)nullptr);
}